// Round 1
// baseline (3091.009 us; speedup 1.0000x reference)
//
#include <hip/hip_runtime.h>
#include <stdint.h>

typedef unsigned long long u64;
typedef unsigned int u32;

__device__ __forceinline__ float rn_mul(float a, float b){ return __fmul_rn(a,b); }
__device__ __forceinline__ float rn_add(float a, float b){ return __fadd_rn(a,b); }
__device__ __forceinline__ float rn_sub(float a, float b){ return __fsub_rn(a,b); }

// ((dx*dx + dy*dy) + dz*dz) with strict rn (matches jnp.sum((a-b)**2, -1))
__device__ __forceinline__ float sq3(float dx, float dy, float dz){
  return rn_add(rn_add(rn_mul(dx,dx), rn_mul(dy,dy)), rn_mul(dz,dz));
}

// monotone float->uint key (handles tiny negative self-distances)
__device__ __forceinline__ u32 fkey(float d){
  u32 b = __float_as_uint(d);
  return b ^ ((u32)((int)b >> 31) | 0x80000000u);
}

__device__ __forceinline__ u64 shfl_xor64(u64 v, int mask){
  int lo = __shfl_xor((int)(u32)v, mask, 64);
  int hi = __shfl_xor((int)(u32)(v >> 32), mask, 64);
  return ((u64)(u32)hi << 32) | (u32)lo;
}

__device__ __forceinline__ u64 umin64(u64 a, u64 b){ return a < b ? a : b; }
__device__ __forceinline__ u64 umax64(u64 a, u64 b){ return a > b ? a : b; }

// ---------------------------------------------------------------------------
// FPS: one block per batch. Points cached in LDS; each thread owns N/NT points
// in registers. Selection: jnp.argmax semantics (first index on ties).
// ---------------------------------------------------------------------------
template<int N, int NT, int M>
__global__ __launch_bounds__(NT)
void fps_kernel(const float* __restrict__ pts, float* __restrict__ npts)
{
  constexpr int PPT = N / NT;
  constexpr int NW  = NT / 64;
  __shared__ float sx[N], sy[N], sz[N];
  __shared__ u64 part[2][NW];
  const int b = blockIdx.x;
  const float* P = pts + (size_t)b * N * 3;
  float* O = npts + (size_t)b * M * 3;
  const int tid = threadIdx.x;

  for (int i = tid; i < N; i += NT){
    sx[i] = P[3*i+0];
    sy[i] = P[3*i+1];
    sz[i] = P[3*i+2];
  }
  __syncthreads();

  float rx[PPT], ry[PPT], rz[PPT], mind[PPT];
  const float c0x = sx[0], c0y = sy[0], c0z = sz[0];
#pragma unroll
  for (int k = 0; k < PPT; ++k){
    const int idx = tid + k*NT;
    rx[k] = sx[idx]; ry[k] = sy[idx]; rz[k] = sz[idx];
    mind[k] = sq3(rn_sub(rx[k],c0x), rn_sub(ry[k],c0y), rn_sub(rz[k],c0z));
  }
  if (tid == 0){ O[0] = c0x; O[1] = c0y; O[2] = c0z; }
  const int lane = tid & 63;
  const int wv   = tid >> 6;

  for (int it = 1; it < M; ++it){
    // local argmax (first index on ties: scan k descending)
    float bm = mind[0];
#pragma unroll
    for (int k = 1; k < PPT; ++k) bm = fmaxf(bm, mind[k]);
    int bk = 0;
#pragma unroll
    for (int k = PPT-1; k >= 0; --k) if (mind[k] == bm) bk = k;
    const u32 gidx = (u32)(tid + bk*NT);
    u64 pk = ((u64)__float_as_uint(bm) << 32) | (u64)(u32)(~gidx);
#pragma unroll
    for (int off = 32; off > 0; off >>= 1){
      u64 o = shfl_xor64(pk, off);
      pk = (o > pk) ? o : pk;
    }
    if (lane == 0) part[it & 1][wv] = pk;
    __syncthreads();           // parity double-buffer -> single barrier/iter
    u64 best = part[it & 1][0];
#pragma unroll
    for (int w = 1; w < NW; ++w){
      u64 o = part[it & 1][w];
      best = (o > best) ? o : best;
    }
    const u32 widx = ~((u32)best);
    const float cx = sx[widx], cy = sy[widx], cz = sz[widx];
    if (tid == 0){ O[3*it+0] = cx; O[3*it+1] = cy; O[3*it+2] = cz; }
#pragma unroll
    for (int k = 0; k < PPT; ++k){
      const float d = sq3(rn_sub(rx[k],cx), rn_sub(ry[k],cy), rn_sub(rz[k],cz));
      mind[k] = fminf(mind[k], d);
    }
  }
}

// ---------------------------------------------------------------------------
// SoA + per-point squared-norm prep (strict rn, matches jnp.sum(pts**2,-1))
// ---------------------------------------------------------------------------
__global__ void prep_kernel(const float* __restrict__ pts, float* __restrict__ px,
                            float* __restrict__ py, float* __restrict__ pz,
                            float* __restrict__ sump, int total)
{
  const int i = blockIdx.x * blockDim.x + threadIdx.x;
  if (i >= total) return;
  const float x = pts[3*i+0], y = pts[3*i+1], z = pts[3*i+2];
  px[i] = x; py[i] = y; pz[i] = z;
  sump[i] = rn_add(rn_add(rn_mul(x,x), rn_mul(y,y)), rn_mul(z,z));
}

// merge my sorted top-4 (asc) with lane^st's sorted top-4 -> sorted 4 smallest
__device__ __forceinline__ void merge4(u64& a0, u64& a1, u64& a2, u64& a3, int st)
{
  const u64 b0 = shfl_xor64(a0, st);
  const u64 b1 = shfl_xor64(a1, st);
  const u64 b2 = shfl_xor64(a2, st);
  const u64 b3 = shfl_xor64(a3, st);
  const u64 m0 = umin64(a0, b3);
  const u64 m1 = umin64(a1, b2);
  const u64 m2 = umin64(a2, b1);
  const u64 m3 = umin64(a3, b0);
  const u64 lo02 = umin64(m0,m2), hi02 = umax64(m0,m2);
  const u64 lo13 = umin64(m1,m3), hi13 = umax64(m1,m3);
  a0 = umin64(lo02, lo13); a1 = umax64(lo02, lo13);
  a2 = umin64(hi02, hi13); a3 = umax64(hi02, hi13);
}

#define KNN_SCAN(Nv)                                                          \
  u64 a0=~0ull, a1=~0ull, a2=~0ull, a3=~0ull;                                 \
  for (int j = r; j < (Nv); j += 4){                                          \
    const float dot = rn_add(rn_add(rn_mul(qx,PX[j]), rn_mul(qy,PY[j])),      \
                             rn_mul(qz,PZ[j]));                               \
    const float d = rn_add(rn_sub(sumq, rn_mul(2.0f, dot)), SP[j]);           \
    const u64 p = ((u64)fkey(d) << 32) | (u32)j;                              \
    if (p < a3){                                                              \
      const bool c2 = p < a2, c1 = p < a1, c0 = p < a0;                       \
      const u64 n3 = c2 ? a2 : p;                                             \
      const u64 n2 = c2 ? (c1 ? a1 : p) : a2;                                 \
      const u64 n1 = c1 ? (c0 ? a0 : p) : a1;                                 \
      const u64 n0 = c0 ? p : a0;                                             \
      a0=n0; a1=n1; a2=n2; a3=n3;                                             \
    }                                                                         \
  }                                                                           \
  merge4(a0,a1,a2,a3,1);                                                      \
  merge4(a0,a1,a2,a3,2);                                                      \
  const u64 selp = (r==0) ? a0 : (r==1) ? a1 : (r==2) ? a2 : a3;              \
  const u32 nidx = (u32)selp;

// ---------------------------------------------------------------------------
// Level-1: kNN(k=4) + PointNet MLP(3->8->16->16) + max over k  -> f1
// 4 lanes per query, 64 queries per 256-thread block.
// ---------------------------------------------------------------------------
template<int N, int M>
__global__ __launch_bounds__(256)
void knn_mlp1_kernel(const float* __restrict__ q,
                     const float* __restrict__ px, const float* __restrict__ py,
                     const float* __restrict__ pz, const float* __restrict__ sp,
                     const float* __restrict__ w1, const float* __restrict__ b1,
                     const float* __restrict__ w2, const float* __restrict__ b2,
                     const float* __restrict__ w3, const float* __restrict__ b3,
                     float* __restrict__ f1)
{
  constexpr int QPB = 64;
  const int blk = blockIdx.x;
  const int b = blk / (M / QPB);
  const int chunk = blk % (M / QPB);
  const int tid = threadIdx.x;
  const int g = tid >> 2;
  const int r = tid & 3;
  const int qi = chunk * QPB + g;
  const float* qp = q + ((size_t)b * M + qi) * 3;
  const float qx = qp[0], qy = qp[1], qz = qp[2];
  const float sumq = rn_add(rn_add(rn_mul(qx,qx), rn_mul(qy,qy)), rn_mul(qz,qz));
  const float* PX = px + (size_t)b * N;
  const float* PY = py + (size_t)b * N;
  const float* PZ = pz + (size_t)b * N;
  const float* SP = sp + (size_t)b * N;

  KNN_SCAN(N)

  const float nx = PX[nidx], ny = PY[nidx], nz = PZ[nidx];
  float h1[8];
#pragma unroll
  for (int c = 0; c < 8; ++c){
    float acc = b1[c];
    acc = fmaf(nx, w1[0*8+c], acc);
    acc = fmaf(ny, w1[1*8+c], acc);
    acc = fmaf(nz, w1[2*8+c], acc);
    h1[c] = fmaxf(acc, 0.0f);
  }
  float h2[16];
#pragma unroll
  for (int c = 0; c < 16; ++c){
    float acc = b2[c];
#pragma unroll
    for (int k = 0; k < 8; ++k) acc = fmaf(h1[k], w2[k*16+c], acc);
    h2[c] = fmaxf(acc, 0.0f);
  }
  float* fo = f1 + ((size_t)b * M + qi) * 16;
#pragma unroll
  for (int c = 0; c < 16; ++c){
    float acc = b3[c];
#pragma unroll
    for (int k = 0; k < 16; ++k) acc = fmaf(h2[k], w3[k*16+c], acc);
    float v = fmaxf(acc, 0.0f);
    v = fmaxf(v, __shfl_xor(v, 1, 64));
    v = fmaxf(v, __shfl_xor(v, 2, 64));
    if (r == 0) fo[c] = v;
  }
}

// ---------------------------------------------------------------------------
// Level-2: kNN(k=4) over npts1 + gather f1 + MLP(16->32->64->64) + max -> f2
// ---------------------------------------------------------------------------
__global__ __launch_bounds__(256)
void knn_mlp2_kernel(const float* __restrict__ q,
                     const float* __restrict__ px, const float* __restrict__ py,
                     const float* __restrict__ pz, const float* __restrict__ sp,
                     const float* __restrict__ f1,
                     const float* __restrict__ w1, const float* __restrict__ b1,
                     const float* __restrict__ w2, const float* __restrict__ b2,
                     const float* __restrict__ w3, const float* __restrict__ b3,
                     float* __restrict__ f2)
{
  constexpr int N = 2048, M = 512, QPB = 64;
  const int blk = blockIdx.x;
  const int b = blk / (M / QPB);
  const int chunk = blk % (M / QPB);
  const int tid = threadIdx.x;
  const int g = tid >> 2;
  const int r = tid & 3;
  const int qi = chunk * QPB + g;
  const float* qp = q + ((size_t)b * M + qi) * 3;
  const float qx = qp[0], qy = qp[1], qz = qp[2];
  const float sumq = rn_add(rn_add(rn_mul(qx,qx), rn_mul(qy,qy)), rn_mul(qz,qz));
  const float* PX = px + (size_t)b * N;
  const float* PY = py + (size_t)b * N;
  const float* PZ = pz + (size_t)b * N;
  const float* SP = sp + (size_t)b * N;

  KNN_SCAN(N)

  const float* fv = f1 + ((size_t)b * 2048 + nidx) * 16;
  float x[16];
#pragma unroll
  for (int i = 0; i < 4; ++i){
    const float4 v = ((const float4*)fv)[i];
    x[4*i+0]=v.x; x[4*i+1]=v.y; x[4*i+2]=v.z; x[4*i+3]=v.w;
  }
  float h1[32];
#pragma unroll
  for (int c = 0; c < 32; ++c){
    float acc = b1[c];
#pragma unroll
    for (int k = 0; k < 16; ++k) acc = fmaf(x[k], w1[k*32+c], acc);
    h1[c] = fmaxf(acc, 0.0f);
  }
  float h2[64];
#pragma unroll
  for (int c = 0; c < 64; ++c){
    float acc = b2[c];
#pragma unroll
    for (int k = 0; k < 32; ++k) acc = fmaf(h1[k], w2[k*64+c], acc);
    h2[c] = fmaxf(acc, 0.0f);
  }
  float* fo = f2 + ((size_t)b * M + qi) * 64;
#pragma unroll
  for (int c = 0; c < 64; ++c){
    float acc = b3[c];
#pragma unroll
    for (int k = 0; k < 64; ++k) acc = fmaf(h2[k], w3[k*64+c], acc);
    float v = fmaxf(acc, 0.0f);
    v = fmaxf(v, __shfl_xor(v, 1, 64));
    v = fmaxf(v, __shfl_xor(v, 2, 64));
    if (r == 0) fo[c] = v;
  }
}

// ---------------------------------------------------------------------------
// Level-3: MLP(64->128->256->256) on f2 + global max over 512 points per batch.
// 16 points per 256-thread block; partial max -> atomicMax (relu >= 0).
// ---------------------------------------------------------------------------
__global__ __launch_bounds__(256)
void mlp3_kernel(const float* __restrict__ f2,
                 const float* __restrict__ w1, const float* __restrict__ b1,
                 const float* __restrict__ w2, const float* __restrict__ b2,
                 const float* __restrict__ w3, const float* __restrict__ b3,
                 float* __restrict__ out)
{
  constexpr int P = 16;
  __shared__ float X [P][64];
  __shared__ float H1[P][128];
  __shared__ float H2[P][256];
  __shared__ float PM[4][256];
  const int blk = blockIdx.x;
  const int b  = blk >> 5;   // 512/16 = 32 chunks per batch
  const int pc = blk & 31;
  const int tid = threadIdx.x;
  const float* F = f2 + ((size_t)b * 512 + (size_t)pc * P) * 64;
  { const float4 v = ((const float4*)F)[tid]; ((float4*)&X[0][0])[tid] = v; }
  __syncthreads();
  { // H1 = relu(X @ w1 + b1): [16,128]
    const int p = tid >> 4, c0 = (tid & 15) * 8;
    float acc[8];
#pragma unroll
    for (int i = 0; i < 8; ++i) acc[i] = b1[c0+i];
    for (int k = 0; k < 64; ++k){
      const float xv = X[p][k];
      const float4 wa = *(const float4*)&w1[k*128 + c0];
      const float4 wb = *(const float4*)&w1[k*128 + c0 + 4];
      acc[0]=fmaf(xv,wa.x,acc[0]); acc[1]=fmaf(xv,wa.y,acc[1]);
      acc[2]=fmaf(xv,wa.z,acc[2]); acc[3]=fmaf(xv,wa.w,acc[3]);
      acc[4]=fmaf(xv,wb.x,acc[4]); acc[5]=fmaf(xv,wb.y,acc[5]);
      acc[6]=fmaf(xv,wb.z,acc[6]); acc[7]=fmaf(xv,wb.w,acc[7]);
    }
#pragma unroll
    for (int i = 0; i < 8; ++i) H1[p][c0+i] = fmaxf(acc[i], 0.0f);
  }
  __syncthreads();
  { // H2 = relu(H1 @ w2 + b2): [16,256]
    const int p = tid >> 4, c0 = (tid & 15) * 16;
    float acc[16];
#pragma unroll
    for (int i = 0; i < 16; ++i) acc[i] = b2[c0+i];
    for (int k = 0; k < 128; ++k){
      const float xv = H1[p][k];
#pragma unroll
      for (int i4 = 0; i4 < 4; ++i4){
        const float4 wv = *(const float4*)&w2[k*256 + c0 + 4*i4];
        acc[4*i4+0]=fmaf(xv,wv.x,acc[4*i4+0]);
        acc[4*i4+1]=fmaf(xv,wv.y,acc[4*i4+1]);
        acc[4*i4+2]=fmaf(xv,wv.z,acc[4*i4+2]);
        acc[4*i4+3]=fmaf(xv,wv.w,acc[4*i4+3]);
      }
    }
#pragma unroll
    for (int i = 0; i < 16; ++i) H2[p][c0+i] = fmaxf(acc[i], 0.0f);
  }
  __syncthreads();
  { // H3 = relu(H2 @ w3 + b3) and max over the block's 16 points
    const int pg = tid >> 6, c0 = (tid & 63) * 4;
    float acc[4][4];
#pragma unroll
    for (int p4 = 0; p4 < 4; ++p4)
#pragma unroll
      for (int i = 0; i < 4; ++i) acc[p4][i] = b3[c0+i];
    for (int k = 0; k < 256; ++k){
      const float4 wv = *(const float4*)&w3[k*256 + c0];
#pragma unroll
      for (int p4 = 0; p4 < 4; ++p4){
        const float xv = H2[pg*4+p4][k];
        acc[p4][0]=fmaf(xv,wv.x,acc[p4][0]);
        acc[p4][1]=fmaf(xv,wv.y,acc[p4][1]);
        acc[p4][2]=fmaf(xv,wv.z,acc[p4][2]);
        acc[p4][3]=fmaf(xv,wv.w,acc[p4][3]);
      }
    }
    float4 mx;
    mx.x = fmaxf(fmaxf(fmaxf(acc[0][0],0.f),fmaxf(acc[1][0],0.f)),
                 fmaxf(fmaxf(acc[2][0],0.f),fmaxf(acc[3][0],0.f)));
    mx.y = fmaxf(fmaxf(fmaxf(acc[0][1],0.f),fmaxf(acc[1][1],0.f)),
                 fmaxf(fmaxf(acc[2][1],0.f),fmaxf(acc[3][1],0.f)));
    mx.z = fmaxf(fmaxf(fmaxf(acc[0][2],0.f),fmaxf(acc[1][2],0.f)),
                 fmaxf(fmaxf(acc[2][2],0.f),fmaxf(acc[3][2],0.f)));
    mx.w = fmaxf(fmaxf(fmaxf(acc[0][3],0.f),fmaxf(acc[1][3],0.f)),
                 fmaxf(fmaxf(acc[2][3],0.f),fmaxf(acc[3][3],0.f)));
    *(float4*)&PM[pg][c0] = mx;
  }
  __syncthreads();
  {
    const float m = fmaxf(fmaxf(PM[0][tid], PM[1][tid]),
                          fmaxf(PM[2][tid], PM[3][tid]));
    atomicMax((int*)(out + b*256 + tid), __float_as_int(m));
  }
}

// ---------------------------------------------------------------------------
extern "C" void kernel_launch(void* const* d_in, const int* in_sizes, int n_in,
                              void* d_out, int out_size, void* d_ws, size_t ws_size,
                              hipStream_t stream)
{
  const float* pts  = (const float*)d_in[0];
  // d_in[1] = batch (int64) -- implied by uniform layout, unused
  const float* p1w1 = (const float*)d_in[2];
  const float* p1b1 = (const float*)d_in[3];
  const float* p1w2 = (const float*)d_in[4];
  const float* p1b2 = (const float*)d_in[5];
  const float* p1w3 = (const float*)d_in[6];
  const float* p1b3 = (const float*)d_in[7];
  const float* p2w1 = (const float*)d_in[8];
  const float* p2b1 = (const float*)d_in[9];
  const float* p2w2 = (const float*)d_in[10];
  const float* p2b2 = (const float*)d_in[11];
  const float* p2w3 = (const float*)d_in[12];
  const float* p2b3 = (const float*)d_in[13];
  const float* p3w1 = (const float*)d_in[14];
  const float* p3b1 = (const float*)d_in[15];
  const float* p3w2 = (const float*)d_in[16];
  const float* p3b2 = (const float*)d_in[17];
  const float* p3w3 = (const float*)d_in[18];
  const float* p3b3 = (const float*)d_in[19];

  float* ws = (float*)d_ws;
  size_t o = 0;
  float* npts1 = ws + o; o += (size_t)8*2048*3;
  float* f1    = ws + o; o += (size_t)8*2048*16;
  float* npts2 = ws + o; o += (size_t)8*512*3;
  float* f2    = ws + o; o += (size_t)8*512*64;
  float* px1   = ws + o; o += (size_t)8*8192;
  float* py1   = ws + o; o += (size_t)8*8192;
  float* pz1   = ws + o; o += (size_t)8*8192;
  float* sp1   = ws + o; o += (size_t)8*8192;
  float* px2   = ws + o; o += (size_t)8*2048;
  float* py2   = ws + o; o += (size_t)8*2048;
  float* pz2   = ws + o; o += (size_t)8*2048;
  float* sp2   = ws + o; o += (size_t)8*2048;

  prep_kernel<<<(8*8192)/256, 256, 0, stream>>>(pts, px1, py1, pz1, sp1, 8*8192);
  fps_kernel<8192,256,2048><<<8, 256, 0, stream>>>(pts, npts1);
  prep_kernel<<<(8*2048)/256, 256, 0, stream>>>(npts1, px2, py2, pz2, sp2, 8*2048);
  knn_mlp1_kernel<8192,2048><<<8*32, 256, 0, stream>>>(npts1, px1, py1, pz1, sp1,
      p1w1, p1b1, p1w2, p1b2, p1w3, p1b3, f1);
  fps_kernel<2048,256,512><<<8, 256, 0, stream>>>(npts1, npts2);
  knn_mlp2_kernel<<<8*8, 256, 0, stream>>>(npts2, px2, py2, pz2, sp2, f1,
      p2w1, p2b1, p2w2, p2b2, p2w3, p2b3, f2);
  hipMemsetAsync(d_out, 0, (size_t)out_size * sizeof(float), stream);
  mlp3_kernel<<<8*32, 256, 0, stream>>>(f2,
      p3w1, p3b1, p3w2, p3b2, p3w3, p3b3, (float*)d_out);
}

// Round 2
// 2992.272 us; speedup vs baseline: 1.0330x; 1.0330x over previous
//
#include <hip/hip_runtime.h>
#include <stdint.h>

typedef unsigned long long u64;
typedef unsigned int u32;

__device__ __forceinline__ float rn_mul(float a, float b){ return __fmul_rn(a,b); }
__device__ __forceinline__ float rn_add(float a, float b){ return __fadd_rn(a,b); }
__device__ __forceinline__ float rn_sub(float a, float b){ return __fsub_rn(a,b); }

// ((dx*dx + dy*dy) + dz*dz) with strict rn (matches jnp.sum((a-b)**2, -1))
__device__ __forceinline__ float sq3(float dx, float dy, float dz){
  return rn_add(rn_add(rn_mul(dx,dx), rn_mul(dy,dy)), rn_mul(dz,dz));
}

// monotone float->uint key (handles tiny negative distances from cancellation)
__device__ __forceinline__ u32 fkey(float d){
  u32 b = __float_as_uint(d);
  return b ^ ((u32)((int)b >> 31) | 0x80000000u);
}

__device__ __forceinline__ u64 shfl_xor64(u64 v, int mask){
  int lo = __shfl_xor((int)(u32)v, mask, 64);
  int hi = __shfl_xor((int)(u32)(v >> 32), mask, 64);
  return ((u64)(u32)hi << 32) | (u32)lo;
}
__device__ __forceinline__ u64 umin64(u64 a, u64 b){ return a < b ? a : b; }
__device__ __forceinline__ u64 umax64(u64 a, u64 b){ return a > b ? a : b; }

// ---------------------------------------------------------------------------
// FPS: one block per batch. float4 coords in LDS; each thread owns N/NT points
// in registers. Fused update+argmax; first-index tie semantics (jnp.argmax).
// ---------------------------------------------------------------------------
template<int N, int NT, int M>
__global__ __launch_bounds__(NT)
void fps_kernel(const float* __restrict__ pts, float* __restrict__ npts)
{
  constexpr int PPT = N / NT;
  constexpr int NW  = NT / 64;
  __shared__ float4 sp[N];
  __shared__ u64 part[2][NW];
  const int b = blockIdx.x;
  const float* P = pts + (size_t)b * N * 3;
  float* O = npts + (size_t)b * M * 3;
  const int tid = threadIdx.x;
  const int lane = tid & 63;
  const int wv   = tid >> 6;

  for (int i = tid; i < N; i += NT)
    sp[i] = make_float4(P[3*i+0], P[3*i+1], P[3*i+2], 0.0f);
  __syncthreads();

  float rx[PPT], ry[PPT], rz[PPT], mind[PPT];
  const float4 c0 = sp[0];
#pragma unroll
  for (int k = 0; k < PPT; ++k){
    const float4 v = sp[tid + k*NT];
    rx[k]=v.x; ry[k]=v.y; rz[k]=v.z;
    mind[k] = sq3(rn_sub(v.x,c0.x), rn_sub(v.y,c0.y), rn_sub(v.z,c0.z));
  }
  if (tid == 0){ O[0]=c0.x; O[1]=c0.y; O[2]=c0.z; }

  float bm; int bk;
  { // local argmax (tree max + first-index rescan)
    float t[PPT];
#pragma unroll
    for (int k=0;k<PPT;++k) t[k]=mind[k];
#pragma unroll
    for (int s=PPT/2;s>0;s>>=1)
#pragma unroll
      for (int i=0;i<s;++i) t[i]=fmaxf(t[i],t[i+s]);
    bm=t[0]; bk=0;
#pragma unroll
    for (int k=PPT-1;k>=0;--k) if (mind[k]==bm) bk=k;
  }

  for (int it = 1; it < M; ++it){
    u64 pk = ((u64)__float_as_uint(bm) << 32) | (u64)(u32)~(u32)(tid + bk*NT);
#pragma unroll
    for (int off = 32; off > 0; off >>= 1)
      pk = umax64(pk, shfl_xor64(pk, off));
    if (lane == 0) part[it & 1][wv] = pk;
    __syncthreads();                    // parity buffers -> single barrier/iter
    u64 best = part[it & 1][lane & (NW-1)];
#pragma unroll
    for (int off = NW/2; off > 0; off >>= 1)
      best = umax64(best, shfl_xor64(best, off));
    const u32 widx = ~(u32)best;
    const float4 c = sp[widx];
    if (tid == 0){ O[3*it+0]=c.x; O[3*it+1]=c.y; O[3*it+2]=c.z; }
    // fused update + local argmax
    float t[PPT];
#pragma unroll
    for (int k = 0; k < PPT; ++k){
      const float d = sq3(rn_sub(rx[k],c.x), rn_sub(ry[k],c.y), rn_sub(rz[k],c.z));
      mind[k] = fminf(mind[k], d);
      t[k] = mind[k];
    }
#pragma unroll
    for (int s=PPT/2;s>0;s>>=1)
#pragma unroll
      for (int i=0;i<s;++i) t[i]=fmaxf(t[i],t[i+s]);
    bm=t[0]; bk=0;
#pragma unroll
    for (int k=PPT-1;k>=0;--k) if (mind[k]==bm) bk=k;
  }
}

// ---------------------------------------------------------------------------
// top-4 (ascending) insertion + cross-lane merge helpers
// ---------------------------------------------------------------------------
__device__ __forceinline__ void top4_insert(u64& a0,u64& a1,u64& a2,u64& a3, u64 p){
  if (p < a3){
    const bool c2 = p < a2, c1 = p < a1, c0 = p < a0;
    const u64 n3 = c2 ? a2 : p;
    const u64 n2 = c2 ? (c1 ? a1 : p) : a2;
    const u64 n1 = c1 ? (c0 ? a0 : p) : a1;
    const u64 n0 = c0 ? p : a0;
    a0=n0; a1=n1; a2=n2; a3=n3;
  }
}

__device__ __forceinline__ void merge4(u64& a0, u64& a1, u64& a2, u64& a3, int st)
{
  const u64 b0 = shfl_xor64(a0, st);
  const u64 b1 = shfl_xor64(a1, st);
  const u64 b2 = shfl_xor64(a2, st);
  const u64 b3 = shfl_xor64(a3, st);
  const u64 m0 = umin64(a0, b3);
  const u64 m1 = umin64(a1, b2);
  const u64 m2 = umin64(a2, b1);
  const u64 m3 = umin64(a3, b0);
  const u64 lo02 = umin64(m0,m2), hi02 = umax64(m0,m2);
  const u64 lo13 = umin64(m1,m3), hi13 = umax64(m1,m3);
  a0 = umin64(lo02, lo13); a1 = umax64(lo02, lo13);
  a2 = umin64(hi02, hi13); a3 = umax64(hi02, hi13);
}

// ---------------------------------------------------------------------------
// Level-1: kNN(k=4) + MLP(3->8->16->16) + max over k -> f1
// 4 lanes/query, 64 queries per 256-thread block; points LDS-staged as
// float4(x,y,z,|p|^2) computed in-kernel (strict rn).
// ---------------------------------------------------------------------------
template<int N, int M, int CH>
__global__ __launch_bounds__(256)
void knn_mlp1_kernel(const float* __restrict__ q, const float* __restrict__ pts,
                     const float* __restrict__ w1, const float* __restrict__ b1,
                     const float* __restrict__ w2, const float* __restrict__ b2,
                     const float* __restrict__ w3, const float* __restrict__ b3,
                     float* __restrict__ f1)
{
  __shared__ float4 s4[CH];
  constexpr int QPB = 64;
  const int blk = blockIdx.x;
  const int b = blk / (M / QPB);
  const int chunk = blk % (M / QPB);
  const int tid = threadIdx.x;
  const int g = tid >> 2;
  const int r = tid & 3;
  const int qi = chunk * QPB + g;
  const float* qp = q + ((size_t)b * M + qi) * 3;
  const float qx = qp[0], qy = qp[1], qz = qp[2];
  const float sumq = rn_add(rn_add(rn_mul(qx,qx), rn_mul(qy,qy)), rn_mul(qz,qz));
  const float* P = pts + (size_t)b * N * 3;

  u64 a0=~0ull, a1=~0ull, a2=~0ull, a3=~0ull;
  for (int c0 = 0; c0 < N; c0 += CH){
    for (int i = tid; i < CH; i += 256){
      const float x = P[3*(c0+i)+0], y = P[3*(c0+i)+1], z = P[3*(c0+i)+2];
      s4[i] = make_float4(x, y, z,
          rn_add(rn_add(rn_mul(x,x), rn_mul(y,y)), rn_mul(z,z)));
    }
    __syncthreads();
#pragma unroll 4
    for (int jj = r; jj < CH; jj += 4){
      const float4 v = s4[jj];
      const float dot = rn_add(rn_add(rn_mul(qx,v.x), rn_mul(qy,v.y)),
                               rn_mul(qz,v.z));
      const float d = rn_add(rn_sub(sumq, rn_mul(2.0f, dot)), v.w);
      top4_insert(a0,a1,a2,a3, ((u64)fkey(d) << 32) | (u32)(c0+jj));
    }
    __syncthreads();
  }
  merge4(a0,a1,a2,a3,1);
  merge4(a0,a1,a2,a3,2);
  const u64 selp = (r==0) ? a0 : (r==1) ? a1 : (r==2) ? a2 : a3;
  const u32 nidx = (u32)selp;

  const float nx = P[3*nidx+0], ny = P[3*nidx+1], nz = P[3*nidx+2];
  float h1[8];
#pragma unroll
  for (int c = 0; c < 8; ++c){
    float acc = b1[c];
    acc = fmaf(nx, w1[0*8+c], acc);
    acc = fmaf(ny, w1[1*8+c], acc);
    acc = fmaf(nz, w1[2*8+c], acc);
    h1[c] = fmaxf(acc, 0.0f);
  }
  float h2[16];
#pragma unroll
  for (int c = 0; c < 16; ++c){
    float acc = b2[c];
#pragma unroll
    for (int k = 0; k < 8; ++k) acc = fmaf(h1[k], w2[k*16+c], acc);
    h2[c] = fmaxf(acc, 0.0f);
  }
  float* fo = f1 + ((size_t)b * M + qi) * 16;
#pragma unroll
  for (int c = 0; c < 16; ++c){
    float acc = b3[c];
#pragma unroll
    for (int k = 0; k < 16; ++k) acc = fmaf(h2[k], w3[k*16+c], acc);
    float v = fmaxf(acc, 0.0f);
    v = fmaxf(v, __shfl_xor(v, 1, 64));
    v = fmaxf(v, __shfl_xor(v, 2, 64));
    if (r == 0) fo[c] = v;
  }
}

// ---------------------------------------------------------------------------
// Level-2: kNN(k=4) over npts1 (all 2048 staged) + gather f1 + MLP -> f2
// ---------------------------------------------------------------------------
__global__ __launch_bounds__(256)
void knn_mlp2_kernel(const float* __restrict__ q, const float* __restrict__ pts,
                     const float* __restrict__ f1,
                     const float* __restrict__ w1, const float* __restrict__ b1,
                     const float* __restrict__ w2, const float* __restrict__ b2,
                     const float* __restrict__ w3, const float* __restrict__ b3,
                     float* __restrict__ f2)
{
  constexpr int N = 2048, M = 512, QPB = 64;
  __shared__ float4 s4[N];
  const int blk = blockIdx.x;
  const int b = blk / (M / QPB);
  const int chunk = blk % (M / QPB);
  const int tid = threadIdx.x;
  const int g = tid >> 2;
  const int r = tid & 3;
  const int qi = chunk * QPB + g;
  const float* qp = q + ((size_t)b * M + qi) * 3;
  const float qx = qp[0], qy = qp[1], qz = qp[2];
  const float sumq = rn_add(rn_add(rn_mul(qx,qx), rn_mul(qy,qy)), rn_mul(qz,qz));
  const float* P = pts + (size_t)b * N * 3;

  for (int i = tid; i < N; i += 256){
    const float x = P[3*i+0], y = P[3*i+1], z = P[3*i+2];
    s4[i] = make_float4(x, y, z,
        rn_add(rn_add(rn_mul(x,x), rn_mul(y,y)), rn_mul(z,z)));
  }
  __syncthreads();

  u64 a0=~0ull, a1=~0ull, a2=~0ull, a3=~0ull;
#pragma unroll 4
  for (int j = r; j < N; j += 4){
    const float4 v = s4[j];
    const float dot = rn_add(rn_add(rn_mul(qx,v.x), rn_mul(qy,v.y)),
                             rn_mul(qz,v.z));
    const float d = rn_add(rn_sub(sumq, rn_mul(2.0f, dot)), v.w);
    top4_insert(a0,a1,a2,a3, ((u64)fkey(d) << 32) | (u32)j);
  }
  merge4(a0,a1,a2,a3,1);
  merge4(a0,a1,a2,a3,2);
  const u64 selp = (r==0) ? a0 : (r==1) ? a1 : (r==2) ? a2 : a3;
  const u32 nidx = (u32)selp;

  const float* fv = f1 + ((size_t)b * 2048 + nidx) * 16;
  float x[16];
#pragma unroll
  for (int i = 0; i < 4; ++i){
    const float4 v = ((const float4*)fv)[i];
    x[4*i+0]=v.x; x[4*i+1]=v.y; x[4*i+2]=v.z; x[4*i+3]=v.w;
  }
  float h1[32];
#pragma unroll
  for (int c = 0; c < 32; ++c){
    float acc = b1[c];
#pragma unroll
    for (int k = 0; k < 16; ++k) acc = fmaf(x[k], w1[k*32+c], acc);
    h1[c] = fmaxf(acc, 0.0f);
  }
  float h2[64];
#pragma unroll
  for (int c = 0; c < 64; ++c){
    float acc = b2[c];
#pragma unroll
    for (int k = 0; k < 32; ++k) acc = fmaf(h1[k], w2[k*64+c], acc);
    h2[c] = fmaxf(acc, 0.0f);
  }
  float* fo = f2 + ((size_t)b * M + qi) * 64;
#pragma unroll
  for (int c = 0; c < 64; ++c){
    float acc = b3[c];
#pragma unroll
    for (int k = 0; k < 64; ++k) acc = fmaf(h2[k], w3[k*64+c], acc);
    float v = fmaxf(acc, 0.0f);
    v = fmaxf(v, __shfl_xor(v, 1, 64));
    v = fmaxf(v, __shfl_xor(v, 2, 64));
    if (r == 0) fo[c] = v;
  }
}

// ---------------------------------------------------------------------------
// Level-3: MLP(64->128->256->256) on f2 + global max over 512 points/batch.
// ---------------------------------------------------------------------------
__global__ __launch_bounds__(256)
void mlp3_kernel(const float* __restrict__ f2,
                 const float* __restrict__ w1, const float* __restrict__ b1,
                 const float* __restrict__ w2, const float* __restrict__ b2,
                 const float* __restrict__ w3, const float* __restrict__ b3,
                 float* __restrict__ out)
{
  constexpr int P = 16;
  __shared__ float X [P][64];
  __shared__ float H1[P][128];
  __shared__ float H2[P][256];
  __shared__ float PM[4][256];
  const int blk = blockIdx.x;
  const int b  = blk >> 5;
  const int pc = blk & 31;
  const int tid = threadIdx.x;
  const float* F = f2 + ((size_t)b * 512 + (size_t)pc * P) * 64;
  { const float4 v = ((const float4*)F)[tid]; ((float4*)&X[0][0])[tid] = v; }
  __syncthreads();
  {
    const int p = tid >> 4, c0 = (tid & 15) * 8;
    float acc[8];
#pragma unroll
    for (int i = 0; i < 8; ++i) acc[i] = b1[c0+i];
    for (int k = 0; k < 64; ++k){
      const float xv = X[p][k];
      const float4 wa = *(const float4*)&w1[k*128 + c0];
      const float4 wb = *(const float4*)&w1[k*128 + c0 + 4];
      acc[0]=fmaf(xv,wa.x,acc[0]); acc[1]=fmaf(xv,wa.y,acc[1]);
      acc[2]=fmaf(xv,wa.z,acc[2]); acc[3]=fmaf(xv,wa.w,acc[3]);
      acc[4]=fmaf(xv,wb.x,acc[4]); acc[5]=fmaf(xv,wb.y,acc[5]);
      acc[6]=fmaf(xv,wb.z,acc[6]); acc[7]=fmaf(xv,wb.w,acc[7]);
    }
#pragma unroll
    for (int i = 0; i < 8; ++i) H1[p][c0+i] = fmaxf(acc[i], 0.0f);
  }
  __syncthreads();
  {
    const int p = tid >> 4, c0 = (tid & 15) * 16;
    float acc[16];
#pragma unroll
    for (int i = 0; i < 16; ++i) acc[i] = b2[c0+i];
    for (int k = 0; k < 128; ++k){
      const float xv = H1[p][k];
#pragma unroll
      for (int i4 = 0; i4 < 4; ++i4){
        const float4 wv = *(const float4*)&w2[k*256 + c0 + 4*i4];
        acc[4*i4+0]=fmaf(xv,wv.x,acc[4*i4+0]);
        acc[4*i4+1]=fmaf(xv,wv.y,acc[4*i4+1]);
        acc[4*i4+2]=fmaf(xv,wv.z,acc[4*i4+2]);
        acc[4*i4+3]=fmaf(xv,wv.w,acc[4*i4+3]);
      }
    }
#pragma unroll
    for (int i = 0; i < 16; ++i) H2[p][c0+i] = fmaxf(acc[i], 0.0f);
  }
  __syncthreads();
  {
    const int pg = tid >> 6, c0 = (tid & 63) * 4;
    float acc[4][4];
#pragma unroll
    for (int p4 = 0; p4 < 4; ++p4)
#pragma unroll
      for (int i = 0; i < 4; ++i) acc[p4][i] = b3[c0+i];
    for (int k = 0; k < 256; ++k){
      const float4 wv = *(const float4*)&w3[k*256 + c0];
#pragma unroll
      for (int p4 = 0; p4 < 4; ++p4){
        const float xv = H2[pg*4+p4][k];
        acc[p4][0]=fmaf(xv,wv.x,acc[p4][0]);
        acc[p4][1]=fmaf(xv,wv.y,acc[p4][1]);
        acc[p4][2]=fmaf(xv,wv.z,acc[p4][2]);
        acc[p4][3]=fmaf(xv,wv.w,acc[p4][3]);
      }
    }
    float4 mx;
    mx.x = fmaxf(fmaxf(fmaxf(acc[0][0],0.f),fmaxf(acc[1][0],0.f)),
                 fmaxf(fmaxf(acc[2][0],0.f),fmaxf(acc[3][0],0.f)));
    mx.y = fmaxf(fmaxf(fmaxf(acc[0][1],0.f),fmaxf(acc[1][1],0.f)),
                 fmaxf(fmaxf(acc[2][1],0.f),fmaxf(acc[3][1],0.f)));
    mx.z = fmaxf(fmaxf(fmaxf(acc[0][2],0.f),fmaxf(acc[1][2],0.f)),
                 fmaxf(fmaxf(acc[2][2],0.f),fmaxf(acc[3][2],0.f)));
    mx.w = fmaxf(fmaxf(fmaxf(acc[0][3],0.f),fmaxf(acc[1][3],0.f)),
                 fmaxf(fmaxf(acc[2][3],0.f),fmaxf(acc[3][3],0.f)));
    *(float4*)&PM[pg][c0] = mx;
  }
  __syncthreads();
  {
    const float m = fmaxf(fmaxf(PM[0][tid], PM[1][tid]),
                          fmaxf(PM[2][tid], PM[3][tid]));
    atomicMax((int*)(out + b*256 + tid), __float_as_int(m));
  }
}

// ---------------------------------------------------------------------------
extern "C" void kernel_launch(void* const* d_in, const int* in_sizes, int n_in,
                              void* d_out, int out_size, void* d_ws, size_t ws_size,
                              hipStream_t stream)
{
  const float* pts  = (const float*)d_in[0];
  // d_in[1] = batch (int64) -- implied by uniform layout, unused
  const float* p1w1 = (const float*)d_in[2];
  const float* p1b1 = (const float*)d_in[3];
  const float* p1w2 = (const float*)d_in[4];
  const float* p1b2 = (const float*)d_in[5];
  const float* p1w3 = (const float*)d_in[6];
  const float* p1b3 = (const float*)d_in[7];
  const float* p2w1 = (const float*)d_in[8];
  const float* p2b1 = (const float*)d_in[9];
  const float* p2w2 = (const float*)d_in[10];
  const float* p2b2 = (const float*)d_in[11];
  const float* p2w3 = (const float*)d_in[12];
  const float* p2b3 = (const float*)d_in[13];
  const float* p3w1 = (const float*)d_in[14];
  const float* p3b1 = (const float*)d_in[15];
  const float* p3w2 = (const float*)d_in[16];
  const float* p3b2 = (const float*)d_in[17];
  const float* p3w3 = (const float*)d_in[18];
  const float* p3b3 = (const float*)d_in[19];

  float* ws = (float*)d_ws;
  size_t o = 0;
  float* npts1 = ws + o; o += (size_t)8*2048*3;
  float* f1    = ws + o; o += (size_t)8*2048*16;
  float* npts2 = ws + o; o += (size_t)8*512*3;
  float* f2    = ws + o; o += (size_t)8*512*64;

  fps_kernel<8192,512,2048><<<8, 512, 0, stream>>>(pts, npts1);
  knn_mlp1_kernel<8192,2048,2048><<<8*32, 256, 0, stream>>>(npts1, pts,
      p1w1, p1b1, p1w2, p1b2, p1w3, p1b3, f1);
  fps_kernel<2048,512,512><<<8, 512, 0, stream>>>(npts1, npts2);
  knn_mlp2_kernel<<<8*8, 256, 0, stream>>>(npts2, npts1, f1,
      p2w1, p2b1, p2w2, p2b2, p2w3, p2b3, f2);
  hipMemsetAsync(d_out, 0, (size_t)out_size * sizeof(float), stream);
  mlp3_kernel<<<8*32, 256, 0, stream>>>(f2,
      p3w1, p3b1, p3w2, p3b2, p3w3, p3b3, (float*)d_out);
}

// Round 3
// 2252.775 us; speedup vs baseline: 1.3721x; 1.3283x over previous
//
#include <hip/hip_runtime.h>
#include <stdint.h>

typedef unsigned long long u64;
typedef unsigned int u32;
typedef float f2 __attribute__((ext_vector_type(2)));

__device__ __forceinline__ float rn_mul(float a, float b){ return __fmul_rn(a,b); }
__device__ __forceinline__ float rn_add(float a, float b){ return __fadd_rn(a,b); }
__device__ __forceinline__ float rn_sub(float a, float b){ return __fsub_rn(a,b); }

__device__ __forceinline__ float sq3(float dx, float dy, float dz){
  return rn_add(rn_add(rn_mul(dx,dx), rn_mul(dy,dy)), rn_mul(dz,dz));
}

// monotone float->uint key (handles tiny negative distances from cancellation)
__device__ __forceinline__ u32 fkey(float d){
  u32 b = __float_as_uint(d);
  return b ^ ((u32)((int)b >> 31) | 0x80000000u);
}

__device__ __forceinline__ u64 shfl_xor64(u64 v, int mask){
  int lo = __shfl_xor((int)(u32)v, mask, 64);
  int hi = __shfl_xor((int)(u32)(v >> 32), mask, 64);
  return ((u64)(u32)hi << 32) | (u32)lo;
}
__device__ __forceinline__ u64 umin64(u64 a, u64 b){ return a < b ? a : b; }
__device__ __forceinline__ u64 umax64(u64 a, u64 b){ return a > b ? a : b; }

// ---- DPP-based max reductions (VALU pipe; old=src so masked/invalid lanes
// are harmless under either bound_ctrl interpretation) ----------------------
template<int C>
__device__ __forceinline__ u32 dstep(u32 v){
  u32 x = (u32)__builtin_amdgcn_update_dpp((int)v, (int)v, C, 0xF, 0xF, false);
  return x > v ? x : v;
}
// full-wave (64) max -> uniform SGPR value
__device__ __forceinline__ u32 wave64_maxu(u32 v){
  v = dstep<0x111>(v);  // row_shr:1
  v = dstep<0x112>(v);  // row_shr:2
  v = dstep<0x114>(v);  // row_shr:4
  v = dstep<0x118>(v);  // row_shr:8
  v = dstep<0x142>(v);  // row_bcast:15
  v = dstep<0x143>(v);  // row_bcast:31
  return (u32)__builtin_amdgcn_readlane((int)v, 63);
}
// max over lanes 0..7 (cross-wave partials) -> uniform SGPR value
__device__ __forceinline__ u32 red8_maxu(u32 v){
  v = dstep<0x111>(v);
  v = dstep<0x112>(v);
  v = dstep<0x114>(v);
  return (u32)__builtin_amdgcn_readlane((int)v, 7);
}

// ---------------------------------------------------------------------------
// FPS: one block per batch, float2-packed per-thread points, DPP argmax.
// Selection semantics = jnp.argmax (max value, first index on ties).
// ---------------------------------------------------------------------------
template<int N, int NT, int M>
__global__ __launch_bounds__(NT)
void fps_kernel(const float* __restrict__ pts, float* __restrict__ npts)
{
  constexpr int PPT = N / NT;
  constexpr int PP2 = PPT / 2;
  constexpr int NW  = NT / 64;
  __shared__ float4 sp[N];
  __shared__ u64 part[2][NW];
  const int b = blockIdx.x;
  const float* P = pts + (size_t)b * N * 3;
  float* O = npts + (size_t)b * M * 3;
  const int tid = threadIdx.x;
  const int lane = tid & 63;
  const int wv   = tid >> 6;

  for (int i = tid; i < N; i += NT)
    sp[i] = make_float4(P[3*i+0], P[3*i+1], P[3*i+2], 0.0f);
  __syncthreads();

  f2 rx[PP2], ry[PP2], rz[PP2], mind[PP2];
  const float4 c0 = sp[0];
#pragma unroll
  for (int j = 0; j < PP2; ++j){
    const float4 va = sp[tid + (2*j+0)*NT];
    const float4 vb = sp[tid + (2*j+1)*NT];
    rx[j] = f2{va.x, vb.x}; ry[j] = f2{va.y, vb.y}; rz[j] = f2{va.z, vb.z};
    const f2 dx = rx[j] - f2{c0.x, c0.x};
    const f2 dy = ry[j] - f2{c0.y, c0.y};
    const f2 dz = rz[j] - f2{c0.z, c0.z};
    mind[j] = ((dx*dx) + (dy*dy)) + (dz*dz);   // v_pk_*, IEEE rn
  }
  if (tid == 0){ O[0]=c0.x; O[1]=c0.y; O[2]=c0.z; }

  float bm; int bk;
  {
    f2 t[PP2];
#pragma unroll
    for (int j=0;j<PP2;++j) t[j]=mind[j];
#pragma unroll
    for (int s=PP2/2;s>0;s>>=1)
#pragma unroll
      for (int i=0;i<s;++i){ t[i].x=fmaxf(t[i].x,t[i+s].x); t[i].y=fmaxf(t[i].y,t[i+s].y); }
    bm = fmaxf(t[0].x, t[0].y);
    bk = 0;
#pragma unroll
    for (int j=PP2-1;j>=0;--j){
      if (mind[j].y == bm) bk = 2*j+1;
      if (mind[j].x == bm) bk = 2*j;
    }
  }

  for (int it = 1; it < M; ++it){
    // in-wave argmax: value phase (bm >= 0 so float order == uint order)
    const u32 wk = wave64_maxu(__float_as_uint(bm));
    const u32 cand = (__float_as_uint(bm) == wk) ? ~(u32)(tid + bk*NT) : 0u;
    const u32 wc = wave64_maxu(cand);
    if (lane == 63) part[it & 1][wv] = ((u64)wk << 32) | wc;
    __syncthreads();                 // parity buffers -> single barrier/iter
    const u64 pp = part[it & 1][lane & (NW-1)];
    const u32 hi = (u32)(pp >> 32), lo = (u32)pp;
    const u32 bmax = red8_maxu(hi);
    const u32 bbest = red8_maxu((hi == bmax) ? lo : 0u);
    const u32 widx = ~bbest;
    const float4 c = sp[widx];
    if (tid == 0){ O[3*it+0]=c.x; O[3*it+1]=c.y; O[3*it+2]=c.z; }
    const f2 cx = {c.x,c.x}, cy = {c.y,c.y}, cz = {c.z,c.z};
    f2 t[PP2];
#pragma unroll
    for (int j = 0; j < PP2; ++j){
      const f2 dx = rx[j]-cx, dy = ry[j]-cy, dz = rz[j]-cz;
      const f2 d = ((dx*dx) + (dy*dy)) + (dz*dz);
      mind[j].x = fminf(mind[j].x, d.x);
      mind[j].y = fminf(mind[j].y, d.y);
      t[j] = mind[j];
    }
#pragma unroll
    for (int s=PP2/2;s>0;s>>=1)
#pragma unroll
      for (int i=0;i<s;++i){ t[i].x=fmaxf(t[i].x,t[i+s].x); t[i].y=fmaxf(t[i].y,t[i+s].y); }
    bm = fmaxf(t[0].x, t[0].y);
    bk = 0;
#pragma unroll
    for (int j=PP2-1;j>=0;--j){
      if (mind[j].y == bm) bk = 2*j+1;
      if (mind[j].x == bm) bk = 2*j;
    }
  }
}

// ---------------------------------------------------------------------------
// top-4 (ascending) insertion + cross-lane merge helpers
// ---------------------------------------------------------------------------
__device__ __forceinline__ void top4_insert(u64& a0,u64& a1,u64& a2,u64& a3, u64 p){
  if (p < a3){
    const bool c2 = p < a2, c1 = p < a1, c0 = p < a0;
    const u64 n3 = c2 ? a2 : p;
    const u64 n2 = c2 ? (c1 ? a1 : p) : a2;
    const u64 n1 = c1 ? (c0 ? a0 : p) : a1;
    const u64 n0 = c0 ? p : a0;
    a0=n0; a1=n1; a2=n2; a3=n3;
  }
}

__device__ __forceinline__ void merge4(u64& a0, u64& a1, u64& a2, u64& a3, int st)
{
  const u64 b0 = shfl_xor64(a0, st);
  const u64 b1 = shfl_xor64(a1, st);
  const u64 b2 = shfl_xor64(a2, st);
  const u64 b3 = shfl_xor64(a3, st);
  const u64 m0 = umin64(a0, b3);
  const u64 m1 = umin64(a1, b2);
  const u64 m2 = umin64(a2, b1);
  const u64 m3 = umin64(a3, b0);
  const u64 lo02 = umin64(m0,m2), hi02 = umax64(m0,m2);
  const u64 lo13 = umin64(m1,m3), hi13 = umax64(m1,m3);
  a0 = umin64(lo02, lo13); a1 = umax64(lo02, lo13);
  a2 = umin64(hi02, hi13); a3 = umax64(hi02, hi13);
}

// ---------------------------------------------------------------------------
// Level-1: kNN(k=4) + MLP(3->8->16->16) + max over k -> f1
// ---------------------------------------------------------------------------
template<int N, int M, int CH>
__global__ __launch_bounds__(256)
void knn_mlp1_kernel(const float* __restrict__ q, const float* __restrict__ pts,
                     const float* __restrict__ w1, const float* __restrict__ b1,
                     const float* __restrict__ w2, const float* __restrict__ b2,
                     const float* __restrict__ w3, const float* __restrict__ b3,
                     float* __restrict__ f1)
{
  __shared__ float4 s4[CH];
  constexpr int QPB = 64;
  const int blk = blockIdx.x;
  const int b = blk / (M / QPB);
  const int chunk = blk % (M / QPB);
  const int tid = threadIdx.x;
  const int g = tid >> 2;
  const int r = tid & 3;
  const int qi = chunk * QPB + g;
  const float* qp = q + ((size_t)b * M + qi) * 3;
  const float qx = qp[0], qy = qp[1], qz = qp[2];
  const float sumq = rn_add(rn_add(rn_mul(qx,qx), rn_mul(qy,qy)), rn_mul(qz,qz));
  const float* P = pts + (size_t)b * N * 3;

  u64 a0=~0ull, a1=~0ull, a2=~0ull, a3=~0ull;
  for (int c0 = 0; c0 < N; c0 += CH){
    for (int i = tid; i < CH; i += 256){
      const float x = P[3*(c0+i)+0], y = P[3*(c0+i)+1], z = P[3*(c0+i)+2];
      s4[i] = make_float4(x, y, z,
          rn_add(rn_add(rn_mul(x,x), rn_mul(y,y)), rn_mul(z,z)));
    }
    __syncthreads();
#pragma unroll 4
    for (int jj = r; jj < CH; jj += 4){
      const float4 v = s4[jj];
      const float dot = rn_add(rn_add(rn_mul(qx,v.x), rn_mul(qy,v.y)),
                               rn_mul(qz,v.z));
      const float d = rn_add(rn_sub(sumq, rn_mul(2.0f, dot)), v.w);
      top4_insert(a0,a1,a2,a3, ((u64)fkey(d) << 32) | (u32)(c0+jj));
    }
    __syncthreads();
  }
  merge4(a0,a1,a2,a3,1);
  merge4(a0,a1,a2,a3,2);
  const u64 selp = (r==0) ? a0 : (r==1) ? a1 : (r==2) ? a2 : a3;
  const u32 nidx = (u32)selp;

  const float nx = P[3*nidx+0], ny = P[3*nidx+1], nz = P[3*nidx+2];
  float h1[8];
#pragma unroll
  for (int c = 0; c < 8; ++c){
    float acc = b1[c];
    acc = fmaf(nx, w1[0*8+c], acc);
    acc = fmaf(ny, w1[1*8+c], acc);
    acc = fmaf(nz, w1[2*8+c], acc);
    h1[c] = fmaxf(acc, 0.0f);
  }
  float h2[16];
#pragma unroll
  for (int c = 0; c < 16; ++c){
    float acc = b2[c];
#pragma unroll
    for (int k = 0; k < 8; ++k) acc = fmaf(h1[k], w2[k*16+c], acc);
    h2[c] = fmaxf(acc, 0.0f);
  }
  float* fo = f1 + ((size_t)b * M + qi) * 16;
#pragma unroll
  for (int c = 0; c < 16; ++c){
    float acc = b3[c];
#pragma unroll
    for (int k = 0; k < 16; ++k) acc = fmaf(h2[k], w3[k*16+c], acc);
    float v = fmaxf(acc, 0.0f);
    v = fmaxf(v, __shfl_xor(v, 1, 64));
    v = fmaxf(v, __shfl_xor(v, 2, 64));
    if (r == 0) fo[c] = v;
  }
}

// ---------------------------------------------------------------------------
// Level-2: kNN(k=4) over npts1 + gather f1 + MLP(16->32->64->64) + max -> f2
// Queries = first 512 rows of npts1 per batch (FPS nesting: fps(npts1,512)
// == npts1[:512] exactly -- same seed, same mind fold order).
// ---------------------------------------------------------------------------
__global__ __launch_bounds__(256)
void knn_mlp2_kernel(const float* __restrict__ q, const float* __restrict__ pts,
                     const float* __restrict__ f1,
                     const float* __restrict__ w1, const float* __restrict__ b1,
                     const float* __restrict__ w2, const float* __restrict__ b2,
                     const float* __restrict__ w3, const float* __restrict__ b3,
                     float* __restrict__ f2)
{
  constexpr int N = 2048, M = 512, QPB = 64, QSTR = 2048;
  __shared__ float4 s4[N];
  const int blk = blockIdx.x;
  const int b = blk / (M / QPB);
  const int chunk = blk % (M / QPB);
  const int tid = threadIdx.x;
  const int g = tid >> 2;
  const int r = tid & 3;
  const int qi = chunk * QPB + g;
  const float* qp = q + ((size_t)b * QSTR + qi) * 3;   // npts1 stride
  const float qx = qp[0], qy = qp[1], qz = qp[2];
  const float sumq = rn_add(rn_add(rn_mul(qx,qx), rn_mul(qy,qy)), rn_mul(qz,qz));
  const float* P = pts + (size_t)b * N * 3;

  for (int i = tid; i < N; i += 256){
    const float x = P[3*i+0], y = P[3*i+1], z = P[3*i+2];
    s4[i] = make_float4(x, y, z,
        rn_add(rn_add(rn_mul(x,x), rn_mul(y,y)), rn_mul(z,z)));
  }
  __syncthreads();

  u64 a0=~0ull, a1=~0ull, a2=~0ull, a3=~0ull;
#pragma unroll 4
  for (int j = r; j < N; j += 4){
    const float4 v = s4[j];
    const float dot = rn_add(rn_add(rn_mul(qx,v.x), rn_mul(qy,v.y)),
                             rn_mul(qz,v.z));
    const float d = rn_add(rn_sub(sumq, rn_mul(2.0f, dot)), v.w);
    top4_insert(a0,a1,a2,a3, ((u64)fkey(d) << 32) | (u32)j);
  }
  merge4(a0,a1,a2,a3,1);
  merge4(a0,a1,a2,a3,2);
  const u64 selp = (r==0) ? a0 : (r==1) ? a1 : (r==2) ? a2 : a3;
  const u32 nidx = (u32)selp;

  const float* fv = f1 + ((size_t)b * 2048 + nidx) * 16;
  float x[16];
#pragma unroll
  for (int i = 0; i < 4; ++i){
    const float4 v = ((const float4*)fv)[i];
    x[4*i+0]=v.x; x[4*i+1]=v.y; x[4*i+2]=v.z; x[4*i+3]=v.w;
  }
  float h1[32];
#pragma unroll
  for (int c = 0; c < 32; ++c){
    float acc = b1[c];
#pragma unroll
    for (int k = 0; k < 16; ++k) acc = fmaf(x[k], w1[k*32+c], acc);
    h1[c] = fmaxf(acc, 0.0f);
  }
  float h2[64];
#pragma unroll
  for (int c = 0; c < 64; ++c){
    float acc = b2[c];
#pragma unroll
    for (int k = 0; k < 32; ++k) acc = fmaf(h1[k], w2[k*64+c], acc);
    h2[c] = fmaxf(acc, 0.0f);
  }
  float* fo = f2 + ((size_t)b * M + qi) * 64;
#pragma unroll
  for (int c = 0; c < 64; ++c){
    float acc = b3[c];
#pragma unroll
    for (int k = 0; k < 64; ++k) acc = fmaf(h2[k], w3[k*64+c], acc);
    float v = fmaxf(acc, 0.0f);
    v = fmaxf(v, __shfl_xor(v, 1, 64));
    v = fmaxf(v, __shfl_xor(v, 2, 64));
    if (r == 0) fo[c] = v;
  }
}

// ---------------------------------------------------------------------------
// Level-3: MLP(64->128->256->256) on f2 + global max over 512 points/batch.
// ---------------------------------------------------------------------------
__global__ __launch_bounds__(256)
void mlp3_kernel(const float* __restrict__ f2,
                 const float* __restrict__ w1, const float* __restrict__ b1,
                 const float* __restrict__ w2, const float* __restrict__ b2,
                 const float* __restrict__ w3, const float* __restrict__ b3,
                 float* __restrict__ out)
{
  constexpr int P = 16;
  __shared__ float X [P][64];
  __shared__ float H1[P][128];
  __shared__ float H2[P][256];
  __shared__ float PM[4][256];
  const int blk = blockIdx.x;
  const int b  = blk >> 5;
  const int pc = blk & 31;
  const int tid = threadIdx.x;
  const float* F = f2 + ((size_t)b * 512 + (size_t)pc * P) * 64;
  { const float4 v = ((const float4*)F)[tid]; ((float4*)&X[0][0])[tid] = v; }
  __syncthreads();
  {
    const int p = tid >> 4, c0 = (tid & 15) * 8;
    float acc[8];
#pragma unroll
    for (int i = 0; i < 8; ++i) acc[i] = b1[c0+i];
    for (int k = 0; k < 64; ++k){
      const float xv = X[p][k];
      const float4 wa = *(const float4*)&w1[k*128 + c0];
      const float4 wb = *(const float4*)&w1[k*128 + c0 + 4];
      acc[0]=fmaf(xv,wa.x,acc[0]); acc[1]=fmaf(xv,wa.y,acc[1]);
      acc[2]=fmaf(xv,wa.z,acc[2]); acc[3]=fmaf(xv,wa.w,acc[3]);
      acc[4]=fmaf(xv,wb.x,acc[4]); acc[5]=fmaf(xv,wb.y,acc[5]);
      acc[6]=fmaf(xv,wb.z,acc[6]); acc[7]=fmaf(xv,wb.w,acc[7]);
    }
#pragma unroll
    for (int i = 0; i < 8; ++i) H1[p][c0+i] = fmaxf(acc[i], 0.0f);
  }
  __syncthreads();
  {
    const int p = tid >> 4, c0 = (tid & 15) * 16;
    float acc[16];
#pragma unroll
    for (int i = 0; i < 16; ++i) acc[i] = b2[c0+i];
    for (int k = 0; k < 128; ++k){
      const float xv = H1[p][k];
#pragma unroll
      for (int i4 = 0; i4 < 4; ++i4){
        const float4 wv = *(const float4*)&w2[k*256 + c0 + 4*i4];
        acc[4*i4+0]=fmaf(xv,wv.x,acc[4*i4+0]);
        acc[4*i4+1]=fmaf(xv,wv.y,acc[4*i4+1]);
        acc[4*i4+2]=fmaf(xv,wv.z,acc[4*i4+2]);
        acc[4*i4+3]=fmaf(xv,wv.w,acc[4*i4+3]);
      }
    }
#pragma unroll
    for (int i = 0; i < 16; ++i) H2[p][c0+i] = fmaxf(acc[i], 0.0f);
  }
  __syncthreads();
  {
    const int pg = tid >> 6, c0 = (tid & 63) * 4;
    float acc[4][4];
#pragma unroll
    for (int p4 = 0; p4 < 4; ++p4)
#pragma unroll
      for (int i = 0; i < 4; ++i) acc[p4][i] = b3[c0+i];
    for (int k = 0; k < 256; ++k){
      const float4 wv = *(const float4*)&w3[k*256 + c0];
#pragma unroll
      for (int p4 = 0; p4 < 4; ++p4){
        const float xv = H2[pg*4+p4][k];
        acc[p4][0]=fmaf(xv,wv.x,acc[p4][0]);
        acc[p4][1]=fmaf(xv,wv.y,acc[p4][1]);
        acc[p4][2]=fmaf(xv,wv.z,acc[p4][2]);
        acc[p4][3]=fmaf(xv,wv.w,acc[p4][3]);
      }
    }
    float4 mx;
    mx.x = fmaxf(fmaxf(fmaxf(acc[0][0],0.f),fmaxf(acc[1][0],0.f)),
                 fmaxf(fmaxf(acc[2][0],0.f),fmaxf(acc[3][0],0.f)));
    mx.y = fmaxf(fmaxf(fmaxf(acc[0][1],0.f),fmaxf(acc[1][1],0.f)),
                 fmaxf(fmaxf(acc[2][1],0.f),fmaxf(acc[3][1],0.f)));
    mx.z = fmaxf(fmaxf(fmaxf(acc[0][2],0.f),fmaxf(acc[1][2],0.f)),
                 fmaxf(fmaxf(acc[2][2],0.f),fmaxf(acc[3][2],0.f)));
    mx.w = fmaxf(fmaxf(fmaxf(acc[0][3],0.f),fmaxf(acc[1][3],0.f)),
                 fmaxf(fmaxf(acc[2][3],0.f),fmaxf(acc[3][3],0.f)));
    *(float4*)&PM[pg][c0] = mx;
  }
  __syncthreads();
  {
    const float m = fmaxf(fmaxf(PM[0][tid], PM[1][tid]),
                          fmaxf(PM[2][tid], PM[3][tid]));
    atomicMax((int*)(out + b*256 + tid), __float_as_int(m));
  }
}

// ---------------------------------------------------------------------------
extern "C" void kernel_launch(void* const* d_in, const int* in_sizes, int n_in,
                              void* d_out, int out_size, void* d_ws, size_t ws_size,
                              hipStream_t stream)
{
  const float* pts  = (const float*)d_in[0];
  // d_in[1] = batch (int64) -- implied by uniform layout, unused
  const float* p1w1 = (const float*)d_in[2];
  const float* p1b1 = (const float*)d_in[3];
  const float* p1w2 = (const float*)d_in[4];
  const float* p1b2 = (const float*)d_in[5];
  const float* p1w3 = (const float*)d_in[6];
  const float* p1b3 = (const float*)d_in[7];
  const float* p2w1 = (const float*)d_in[8];
  const float* p2b1 = (const float*)d_in[9];
  const float* p2w2 = (const float*)d_in[10];
  const float* p2b2 = (const float*)d_in[11];
  const float* p2w3 = (const float*)d_in[12];
  const float* p2b3 = (const float*)d_in[13];
  const float* p3w1 = (const float*)d_in[14];
  const float* p3b1 = (const float*)d_in[15];
  const float* p3w2 = (const float*)d_in[16];
  const float* p3b2 = (const float*)d_in[17];
  const float* p3w3 = (const float*)d_in[18];
  const float* p3b3 = (const float*)d_in[19];

  float* ws = (float*)d_ws;
  size_t o = 0;
  float* npts1 = ws + o; o += (size_t)8*2048*3;
  float* f1    = ws + o; o += (size_t)8*2048*16;
  float* f2    = ws + o; o += (size_t)8*512*64;

  fps_kernel<8192,512,2048><<<8, 512, 0, stream>>>(pts, npts1);
  knn_mlp1_kernel<8192,2048,2048><<<8*32, 256, 0, stream>>>(npts1, pts,
      p1w1, p1b1, p1w2, p1b2, p1w3, p1b3, f1);
  // fps level-2 eliminated: fps(npts1,512) == npts1[:512] (nesting property)
  knn_mlp2_kernel<<<8*8, 256, 0, stream>>>(npts1, npts1, f1,
      p2w1, p2b1, p2w2, p2b2, p2w3, p2b3, f2);
  hipMemsetAsync(d_out, 0, (size_t)out_size * sizeof(float), stream);
  mlp3_kernel<<<8*32, 256, 0, stream>>>(f2,
      p3w1, p3b1, p3w2, p3b2, p3w3, p3b3, (float*)d_out);
}